// Round 2
// baseline (466.293 us; speedup 1.0000x reference)
//
#include <hip/hip_runtime.h>

// EventMessagePassingEdge: per-edge 2-layer MLP with gathered node features.
//   evt[e] = [h[src[e]], e_h[e], h[dst[e]]]           (192 fp32)
//   x      = evt @ W1 + b1                            (64)
//   out    = relu([x, ext[e]] @ W2 + b2)              (64 fp32)
// V3 strategy (depth-2 register pipeline — V2 showed the kernel is
// latency-bound on the per-iteration gather wait, NOT wave-starved):
//   - A-fragment gathers for iteration it+1 are ISSUED before compute of
//     iteration it (double-buffered f32x4 LA/LB, 96 VGPRs). The ~600-900 cyc
//     random-gather latency hides under the previous iteration's MFMA+LDS.
//   - src/dst indices prefetched one stage earlier still.
//   - 256-thread blocks: LDS = 36 KB W-frags + 4x3 KB x2 = 48 KB
//     -> 3 blocks/CU = 12 waves/CU. __launch_bounds__(256,3) caps VGPR ~168.
// W1/W2 staged once per block in LDS in B-fragment order (conflict-free b128).
// No __syncthreads in main loop.

typedef __attribute__((ext_vector_type(8))) short bf16x8;
typedef __attribute__((ext_vector_type(4))) float f32x4;
typedef __attribute__((ext_vector_type(4))) short s16x4;

__device__ __forceinline__ short f2bf(float f) {
  // round-to-nearest-even fp32 -> bf16
  unsigned u = __builtin_bit_cast(unsigned, f);
  u = (u + 0x7FFFu + ((u >> 16) & 1u)) >> 16;
  return (short)u;
}

#define ITERS 4  // 4 waves * 16 edges * 4 iters = 256 edges/block

// LDS layout (shorts):
//   [0,     12288)  W1 frags: slot s = (kc*4+nt)*64 + lane, 8 bf16 each
//   [12288, 18432)  W2 frags: slot s = (kc*4+nt)*64 + lane, 8 bf16 each
//   [18432, 24576)  per-wave x2 region, 1536 shorts (3072 B) per wave (4 waves)
//     x2 slot = kc*64 + quad*16 + m (kc 0..2) holds x2[m][kc*32+quad*8+j]
// total 49152 B -> 3 blocks/CU.

__global__ __launch_bounds__(256, 3) void edge_mp_kernel(
    const float* __restrict__ h, const float* __restrict__ e_h,
    const float* __restrict__ ext, const float* __restrict__ W1,
    const float* __restrict__ b1, const float* __restrict__ W2,
    const float* __restrict__ b2, const int* __restrict__ src,
    const int* __restrict__ dst, float* __restrict__ out, int E) {
  __shared__ __align__(16) short lds[24576];
  const int tid = threadIdx.x;
  const int l = tid & 63;   // lane
  const int wid = tid >> 6; // wave in block (0..3)
  const int i = l & 15;     // MFMA idx (col of C, row of A) = edge within tile
  const int q = l >> 4;     // MFMA quad
  const int i2 = l >> 2;    // ext staging: edge within tile
  const int c = l & 3;      // ext staging: chunk lane

  // ---- stage W1 fragments (1536 slots) ----
  for (int s = tid; s < 1536; s += 256) {
    int kc = s >> 8, nt = (s >> 6) & 3, ll = s & 63;
    int k0 = kc * 32 + ((ll >> 4) * 8), n = nt * 16 + (ll & 15);
#pragma unroll
    for (int j = 0; j < 8; ++j) lds[s * 8 + j] = f2bf(W1[(k0 + j) * 64 + n]);
  }
  // ---- stage W2 fragments (768 slots) ----
  for (int s = tid; s < 768; s += 256) {
    int kc = s >> 8, nt = (s >> 6) & 3, ll = s & 63;
    int k0 = kc * 32 + ((ll >> 4) * 8), n = nt * 16 + (ll & 15);
#pragma unroll
    for (int j = 0; j < 8; ++j)
      lds[12288 + s * 8 + j] = f2bf(W2[(k0 + j) * 64 + n]);
  }
  __syncthreads();

  float b1v[4], b2v[4];
#pragma unroll
  for (int nt = 0; nt < 4; ++nt) {
    b1v[nt] = b1[nt * 16 + i];
    b2v[nt] = b2[nt * 16 + i];
  }

  short* xw = &lds[18432 + wid * 1536];

  // wave's edge slice: e0(it) = blockIdx.x*256 + it*64 + wid*16
  const int wbase = blockIdx.x * 256 + wid * 16;

  auto clampE = [E](int e) { return e < E ? e : E - 1; };

  // issue the 12 layer-1 A-fragment gathers (direct to registers, in flight)
  auto issue = [&](f32x4* L, int nS, int nD, int e) {
    const float* ps = h + (size_t)nS * 64 + q * 8;
    const float* pe = e_h + (size_t)e * 64 + q * 8;
    const float* pd = h + (size_t)nD * 64 + q * 8;
    L[0] = *(const f32x4*)(ps);
    L[1] = *(const f32x4*)(ps + 4);
    L[2] = *(const f32x4*)(ps + 32);
    L[3] = *(const f32x4*)(ps + 36);
    L[4] = *(const f32x4*)(pe);
    L[5] = *(const f32x4*)(pe + 4);
    L[6] = *(const f32x4*)(pe + 32);
    L[7] = *(const f32x4*)(pe + 36);
    L[8] = *(const f32x4*)(pd);
    L[9] = *(const f32x4*)(pd + 4);
    L[10] = *(const f32x4*)(pd + 32);
    L[11] = *(const f32x4*)(pd + 36);
  };

  // full per-tile compute: layer1 (A from regs), x2 LDS round-trip, layer2,
  // epilogue store. ext loads issued at top so they fly under layer 1.
  auto compute = [&](const f32x4* L, int e0) {
    int ex = clampE(e0 + i2);
    f32x4 X0 = *(const f32x4*)(ext + (size_t)ex * 32 + 4 * c);
    f32x4 X1 = *(const f32x4*)(ext + (size_t)ex * 32 + 16 + 4 * c);

    // ---- layer 1: 6 kc x 4 ntile MFMAs, A from registers ----
    f32x4 acc[4] = {{0.f, 0.f, 0.f, 0.f},
                    {0.f, 0.f, 0.f, 0.f},
                    {0.f, 0.f, 0.f, 0.f},
                    {0.f, 0.f, 0.f, 0.f}};
#pragma unroll
    for (int kc = 0; kc < 6; ++kc) {
      bf16x8 a;
#pragma unroll
      for (int j = 0; j < 4; ++j) {
        a[j] = f2bf(L[2 * kc][j]);
        a[4 + j] = f2bf(L[2 * kc + 1][j]);
      }
#pragma unroll
      for (int nt = 0; nt < 4; ++nt) {
        bf16x8 b = *(const bf16x8*)&lds[((kc * 4 + nt) * 64 + l) * 8];
        acc[nt] =
            __builtin_amdgcn_mfma_f32_16x16x32_bf16(a, b, acc[nt], 0, 0, 0);
      }
    }

    // ---- x (C-layout) + b1 -> bf16 -> x2 A-layout in LDS ----
#pragma unroll
    for (int nt = 0; nt < 4; ++nt) {
      const int n = nt * 16 + i;
      const int kc2 = n >> 5, qA = (n & 31) >> 3, j = n & 7;
#pragma unroll
      for (int r = 0; r < 4; ++r) {
        const int m = q * 4 + r;  // C row = edge within tile
        xw[(kc2 * 64 + qA * 16 + m) * 8 + j] = f2bf(acc[nt][r] + b1v[nt]);
      }
    }
    // ---- ext -> x2 chunk kc2 = 2 ----
#pragma unroll
    for (int t = 0; t < 2; ++t) {
      f32x4 v = t ? X1 : X0;
      const int quad = 2 * t + (c >> 1);
      const int j0 = 4 * (c & 1);
      s16x4 p;
      p[0] = f2bf(v[0]);
      p[1] = f2bf(v[1]);
      p[2] = f2bf(v[2]);
      p[3] = f2bf(v[3]);
      *(s16x4*)&xw[(2 * 64 + quad * 16 + i2) * 8 + j0] = p;
    }

    // ---- layer 2: 3 kc x 4 ntile MFMAs ----
    f32x4 acc2[4] = {{0.f, 0.f, 0.f, 0.f},
                     {0.f, 0.f, 0.f, 0.f},
                     {0.f, 0.f, 0.f, 0.f},
                     {0.f, 0.f, 0.f, 0.f}};
#pragma unroll
    for (int kc = 0; kc < 3; ++kc) {
      bf16x8 a = *(const bf16x8*)&xw[(kc * 64 + l) * 8];
#pragma unroll
      for (int nt = 0; nt < 4; ++nt) {
        bf16x8 b = *(const bf16x8*)&lds[12288 + ((kc * 4 + nt) * 64 + l) * 8];
        acc2[nt] =
            __builtin_amdgcn_mfma_f32_16x16x32_bf16(a, b, acc2[nt], 0, 0, 0);
      }
    }

    // ---- epilogue: +b2, relu, store fp32 (C-layout) ----
#pragma unroll
    for (int nt = 0; nt < 4; ++nt) {
      const int n = nt * 16 + i;
#pragma unroll
      for (int r = 0; r < 4; ++r) {
        const int er = e0 + q * 4 + r;
        if (er < E) {
          float v = acc2[nt][r] + b2v[nt];
          out[(size_t)er * 64 + n] = fmaxf(v, 0.f);
        }
      }
    }
  };

  // ---- depth-2 software pipeline over ITERS=4 tiles ----
  f32x4 LA[12], LB[12];

  // prologue: indices for tiles 0 and 1, then gathers for both in flight
  int eA = clampE(wbase + 0 * 64 + i);
  int sA = src[eA], dA = dst[eA];
  int eB = clampE(wbase + 1 * 64 + i);
  int sB = src[eB], dB = dst[eB];
  issue(LA, sA, dA, eA);
  issue(LB, sB, dB, eB);

  // prefetch indices for tile 2
  eA = clampE(wbase + 2 * 64 + i);
  sA = src[eA];
  dA = dst[eA];

  compute(LA, wbase + 0 * 64);  // tile 0 (LB gathers in flight)

  issue(LA, sA, dA, eA);        // gathers for tile 2
  eB = clampE(wbase + 3 * 64 + i);
  sB = src[eB];
  dB = dst[eB];

  compute(LB, wbase + 1 * 64);  // tile 1 (LA gathers in flight)

  issue(LB, sB, dB, eB);        // gathers for tile 3

  compute(LA, wbase + 2 * 64);  // tile 2 (LB gathers in flight)
  compute(LB, wbase + 3 * 64);  // tile 3
}

extern "C" void kernel_launch(void* const* d_in, const int* in_sizes, int n_in,
                              void* d_out, int out_size, void* d_ws,
                              size_t ws_size, hipStream_t stream) {
  const float* h = (const float*)d_in[0];
  const float* e_h = (const float*)d_in[1];
  const float* ext = (const float*)d_in[2];
  const float* W1 = (const float*)d_in[3];
  const float* b1 = (const float*)d_in[4];
  const float* W2 = (const float*)d_in[5];
  const float* b2 = (const float*)d_in[6];
  const int* src = (const int*)d_in[7];
  const int* dst = (const int*)d_in[8];
  float* out = (float*)d_out;
  const int E = in_sizes[7];  // 800000
  const int blocks = (E + 255) / 256;  // 256 edges per block
  hipLaunchKernelGGL(edge_mp_kernel, dim3(blocks), dim3(256), 0, stream, h, e_h,
                     ext, W1, b1, W2, b2, src, dst, out, E);
}

// Round 3
// 453.905 us; speedup vs baseline: 1.0273x; 1.0273x over previous
//
#include <hip/hip_runtime.h>

// EventMessagePassingEdge: per-edge 2-layer MLP with gathered node features.
//   evt[e] = [h[src[e]], e_h[e], h[dst[e]]]           (192 fp32)
//   x      = evt @ W1 + b1                            (64)
//   out    = relu([x, ext[e]] @ W2 + b2)              (64 fp32)
// V4 strategy (VMEM request-rate fix):
//   V1/V2/V3 all ran ~175-182us at ~3 TB/s regardless of occupancy or
//   pipelining -> limiter is the per-CU L1 request rate (~1 lane-request/cyc).
//   Slot census per 16-edge tile: gathers 768, ext 128, idx 2, STORES 1024
//   (16x global_store_dword = 4 B/lane!). Fix: transpose the C-tile through
//   the per-wave LDS buffer and store 4x global_store_dwordx4 (16 B/lane,
//   256 slots). Expected ~40% fewer slots -> ~110-125 us.
//   - Layer-1 A-fragments gathered direct global->register (V2 pattern).
//   - 256-thread blocks; LDS = 36 KB W-frags + 4 x 4 KB per-wave buffers
//     = 52 KB -> 3 blocks/CU.
// W1/W2 staged once per block in LDS in B-fragment order (conflict-free b128).
// No __syncthreads in main loop.

typedef __attribute__((ext_vector_type(8))) short bf16x8;
typedef __attribute__((ext_vector_type(4))) float f32x4;
typedef __attribute__((ext_vector_type(4))) short s16x4;

__device__ __forceinline__ short f2bf(float f) {
  // round-to-nearest-even fp32 -> bf16
  unsigned u = __builtin_bit_cast(unsigned, f);
  u = (u + 0x7FFFu + ((u >> 16) & 1u)) >> 16;
  return (short)u;
}

#define ITERS 4  // 4 waves * 16 edges * 4 iters = 256 edges/block

// LDS layout (shorts):
//   [0,     12288)  W1 frags: slot s = (kc*4+nt)*64 + lane, 8 bf16 each
//   [12288, 18432)  W2 frags: slot s = (kc*4+nt)*64 + lane, 8 bf16 each
//   [18432, 26624)  per-wave 2048-short (4 KB) buffer (4 waves):
//       shorts 0..1535: x2 A-frags  (layer-2 input round-trip)
//       floats 0..1023 (aliased):   out-tile transpose buffer (epilogue)
//     Aliasing is safe: DS ops from one wave execute in order, buffer is
//     per-wave, and x2 reads complete before the epilogue writes.
// total 53248 B -> 3 blocks/CU.

__global__ __launch_bounds__(256, 3) void edge_mp_kernel(
    const float* __restrict__ h, const float* __restrict__ e_h,
    const float* __restrict__ ext, const float* __restrict__ W1,
    const float* __restrict__ b1, const float* __restrict__ W2,
    const float* __restrict__ b2, const int* __restrict__ src,
    const int* __restrict__ dst, float* __restrict__ out, int E) {
  __shared__ __align__(16) short lds[26624];
  const int tid = threadIdx.x;
  const int l = tid & 63;   // lane
  const int wid = tid >> 6; // wave in block (0..3)
  const int i = l & 15;     // MFMA idx (col of C, row of A) = edge within tile
  const int q = l >> 4;     // MFMA quad
  const int i2 = l >> 2;    // ext staging: edge within tile
  const int c = l & 3;      // ext staging: chunk lane

  // ---- stage W1 fragments (1536 slots) ----
  for (int s = tid; s < 1536; s += 256) {
    int kc = s >> 8, nt = (s >> 6) & 3, ll = s & 63;
    int k0 = kc * 32 + ((ll >> 4) * 8), n = nt * 16 + (ll & 15);
#pragma unroll
    for (int j = 0; j < 8; ++j) lds[s * 8 + j] = f2bf(W1[(k0 + j) * 64 + n]);
  }
  // ---- stage W2 fragments (768 slots) ----
  for (int s = tid; s < 768; s += 256) {
    int kc = s >> 8, nt = (s >> 6) & 3, ll = s & 63;
    int k0 = kc * 32 + ((ll >> 4) * 8), n = nt * 16 + (ll & 15);
#pragma unroll
    for (int j = 0; j < 8; ++j)
      lds[12288 + s * 8 + j] = f2bf(W2[(k0 + j) * 64 + n]);
  }
  __syncthreads();

  float b1v[4], b2v[4];
#pragma unroll
  for (int nt = 0; nt < 4; ++nt) {
    b1v[nt] = b1[nt * 16 + i];
    b2v[nt] = b2[nt * 16 + i];
  }

  short* xw = &lds[18432 + wid * 2048];
  float* ow = (float*)xw;  // aliased out-transpose buffer (1024 f32)

  // wave's edge slice: e0(it) = blockIdx.x*256 + it*64 + wid*16
  const int wbase = blockIdx.x * 256 + wid * 16;

  // prefetch first iteration's indices
  int nS = 0, nD = 0;
  if (wbase < E) {
    int e = wbase + i;
    if (e >= E) e = E - 1;
    nS = src[e];
    nD = dst[e];
  }

#pragma unroll 1
  for (int it = 0; it < ITERS; ++it) {
    const int e0 = wbase + it * 64;
    if (e0 >= E) break;
    int e = e0 + i;
    if (e >= E) e = E - 1;

    // ---- layer-1 A-fragment gathers (direct to registers) ----
    // lane (i,q): 8 contiguous floats at k_local = t*32 + q*8 per source.
    const float* ps = h + (size_t)nS * 64 + q * 8;
    const float* pe = e_h + (size_t)e * 64 + q * 8;
    const float* pd = h + (size_t)nD * 64 + q * 8;
    f32x4 L[12];
    L[0] = *(const f32x4*)(ps);
    L[1] = *(const f32x4*)(ps + 4);
    L[2] = *(const f32x4*)(ps + 32);
    L[3] = *(const f32x4*)(ps + 36);
    L[4] = *(const f32x4*)(pe);
    L[5] = *(const f32x4*)(pe + 4);
    L[6] = *(const f32x4*)(pe + 32);
    L[7] = *(const f32x4*)(pe + 36);
    L[8] = *(const f32x4*)(pd);
    L[9] = *(const f32x4*)(pd + 4);
    L[10] = *(const f32x4*)(pd + 32);
    L[11] = *(const f32x4*)(pd + 36);

    // ---- ext loads (coalesced, i2/c pattern) ----
    int ex = e0 + i2;
    if (ex >= E) ex = E - 1;
    f32x4 X0 = *(const f32x4*)(ext + (size_t)ex * 32 + 4 * c);
    f32x4 X1 = *(const f32x4*)(ext + (size_t)ex * 32 + 16 + 4 * c);

    // ---- prefetch next iteration's indices (off the critical chain) ----
    if (it + 1 < ITERS) {
      const int en0 = e0 + 64;
      if (en0 < E) {
        int en = en0 + i;
        if (en >= E) en = E - 1;
        nS = src[en];
        nD = dst[en];
      }
    }

    // ---- layer 1: 6 kc x 4 ntile MFMAs, A from registers ----
    f32x4 acc[4] = {{0.f, 0.f, 0.f, 0.f},
                    {0.f, 0.f, 0.f, 0.f},
                    {0.f, 0.f, 0.f, 0.f},
                    {0.f, 0.f, 0.f, 0.f}};
#pragma unroll
    for (int kc = 0; kc < 6; ++kc) {
      bf16x8 a;
#pragma unroll
      for (int j = 0; j < 4; ++j) {
        a[j] = f2bf(L[2 * kc][j]);
        a[4 + j] = f2bf(L[2 * kc + 1][j]);
      }
#pragma unroll
      for (int nt = 0; nt < 4; ++nt) {
        bf16x8 b = *(const bf16x8*)&lds[((kc * 4 + nt) * 64 + l) * 8];
        acc[nt] =
            __builtin_amdgcn_mfma_f32_16x16x32_bf16(a, b, acc[nt], 0, 0, 0);
      }
    }

    // ---- x (C-layout) + b1 -> bf16 -> x2 A-layout in LDS ----
#pragma unroll
    for (int nt = 0; nt < 4; ++nt) {
      const int n = nt * 16 + i;
      const int kc2 = n >> 5, qA = (n & 31) >> 3, j = n & 7;
#pragma unroll
      for (int r = 0; r < 4; ++r) {
        const int m = q * 4 + r;  // C row = edge within tile
        xw[(kc2 * 64 + qA * 16 + m) * 8 + j] = f2bf(acc[nt][r] + b1v[nt]);
      }
    }
    // ---- ext -> x2 chunk kc2 = 2 ----
#pragma unroll
    for (int t = 0; t < 2; ++t) {
      f32x4 v = t ? X1 : X0;
      const int quad = 2 * t + (c >> 1);
      const int j0 = 4 * (c & 1);
      s16x4 p;
      p[0] = f2bf(v[0]);
      p[1] = f2bf(v[1]);
      p[2] = f2bf(v[2]);
      p[3] = f2bf(v[3]);
      *(s16x4*)&xw[(2 * 64 + quad * 16 + i2) * 8 + j0] = p;
    }

    // ---- layer 2: 3 kc x 4 ntile MFMAs ----
    f32x4 acc2[4] = {{0.f, 0.f, 0.f, 0.f},
                     {0.f, 0.f, 0.f, 0.f},
                     {0.f, 0.f, 0.f, 0.f},
                     {0.f, 0.f, 0.f, 0.f}};
#pragma unroll
    for (int kc = 0; kc < 3; ++kc) {
      bf16x8 a = *(const bf16x8*)&xw[(kc * 64 + l) * 8];
#pragma unroll
      for (int nt = 0; nt < 4; ++nt) {
        bf16x8 b = *(const bf16x8*)&lds[12288 + ((kc * 4 + nt) * 64 + l) * 8];
        acc2[nt] =
            __builtin_amdgcn_mfma_f32_16x16x32_bf16(a, b, acc2[nt], 0, 0, 0);
      }
    }

    // ---- epilogue: +b2, relu; transpose via LDS; 16 B/lane stores ----
    if (e0 + 15 < E) {
      // write C-layout f32 to LDS, bank-swizzled (2-way max = free).
      // word addr = row*64 + (n ^ ((row>>2 & 1)<<4))
#pragma unroll
      for (int nt = 0; nt < 4; ++nt) {
        const int n = nt * 16 + i;
#pragma unroll
        for (int r = 0; r < 4; ++r) {
          const int row = q * 4 + r;
          const int nsw = n ^ (((row >> 2) & 1) << 4);
          ow[row * 64 + nsw] = fmaxf(acc2[nt][r] + b2v[nt], 0.f);
        }
      }
      // read back row-major (swizzle uniform per instr) and store dwordx4.
      // instr t: lane (i,q) -> row t*4+q, cols 4i..4i+3 -> 1 KB contiguous.
#pragma unroll
      for (int t = 0; t < 4; ++t) {
        const int row = t * 4 + q;
        const int n0 = 4 * i;
        const int nsw = n0 ^ (((row >> 2) & 1) << 4);
        f32x4 v = *(const f32x4*)&ow[row * 64 + nsw];
        *(f32x4*)&out[(size_t)(e0 + row) * 64 + n0] = v;
      }
    } else {
      // tail tile: guarded scalar stores (C-layout)
#pragma unroll
      for (int nt = 0; nt < 4; ++nt) {
        const int n = nt * 16 + i;
#pragma unroll
        for (int r = 0; r < 4; ++r) {
          const int er = e0 + q * 4 + r;
          if (er < E) {
            float v = acc2[nt][r] + b2v[nt];
            out[(size_t)er * 64 + n] = fmaxf(v, 0.f);
          }
        }
      }
    }
  }
}

extern "C" void kernel_launch(void* const* d_in, const int* in_sizes, int n_in,
                              void* d_out, int out_size, void* d_ws,
                              size_t ws_size, hipStream_t stream) {
  const float* h = (const float*)d_in[0];
  const float* e_h = (const float*)d_in[1];
  const float* ext = (const float*)d_in[2];
  const float* W1 = (const float*)d_in[3];
  const float* b1 = (const float*)d_in[4];
  const float* W2 = (const float*)d_in[5];
  const float* b2 = (const float*)d_in[6];
  const int* src = (const int*)d_in[7];
  const int* dst = (const int*)d_in[8];
  float* out = (float*)d_out;
  const int E = in_sizes[7];  // 800000
  const int blocks = (E + 255) / 256;  // 256 edges per block
  hipLaunchKernelGGL(edge_mp_kernel, dim3(blocks), dim3(256), 0, stream, h, e_h,
                     ext, W1, b1, W2, b2, src, dst, out, E);
}

// Round 4
// 443.513 us; speedup vs baseline: 1.0514x; 1.0234x over previous
//
#include <hip/hip_runtime.h>

// EventMessagePassingEdge: per-edge 2-layer MLP with gathered node features.
//   evt[e] = [h[src[e]], e_h[e], h[dst[e]]]           (192 fp32)
//   x      = evt @ W1 + b1                            (64)
//   out    = relu([x, ext[e]] @ W2 + b2)              (64 fp32)
// V5 strategy (gather-miss-path fix):
//   V1-V4 all ran 171-182us regardless of occupancy, pipelining, or store
//   coalescing. Invariant = the random h-gather: 2 x 256 B fp32 per edge from
//   a 12.8 MB table -> every line misses L1, ~69% miss the 4 MB per-XCD L2.
//   Per-CU outstanding-miss capacity / latency caps line throughput; no wave
//   count or schedule raises it. Fix: one-time prepass converts h -> bf16
//   table in workspace (6.4 MB): half the gather lines, ~2x L2 hit rate, and
//   the gathered bf16x8 IS the MFMA A-fragment (no f2bf on the h side).
//   - V4's coalesced dwordx4 store epilogue retained.
//   - 256-thread blocks; LDS 52 KB -> 3 blocks/CU.
// W1/W2 staged once per block in LDS in B-fragment order (conflict-free b128).
// No __syncthreads in main loop.

typedef __attribute__((ext_vector_type(8))) short bf16x8;
typedef __attribute__((ext_vector_type(4))) float f32x4;
typedef __attribute__((ext_vector_type(4))) short s16x4;

__device__ __forceinline__ short f2bf(float f) {
  // round-to-nearest-even fp32 -> bf16
  unsigned u = __builtin_bit_cast(unsigned, f);
  u = (u + 0x7FFFu + ((u >> 16) & 1u)) >> 16;
  return (short)u;
}

#define ITERS 4  // 4 waves * 16 edges * 4 iters = 256 edges/block

// ---- prepass: h (fp32) -> bf16 table in workspace ----
__global__ __launch_bounds__(256) void h2bf_kernel(
    const float* __restrict__ h, ushort* __restrict__ hb, int n4) {
  int idx = blockIdx.x * 256 + threadIdx.x;  // one float4 per thread
  if (idx < n4) {
    f32x4 v = ((const f32x4*)h)[idx];
    s16x4 p;
    p[0] = f2bf(v[0]);
    p[1] = f2bf(v[1]);
    p[2] = f2bf(v[2]);
    p[3] = f2bf(v[3]);
    ((s16x4*)hb)[idx] = p;
  }
}

// LDS layout (shorts):
//   [0,     12288)  W1 frags: slot s = (kc*4+nt)*64 + lane, 8 bf16 each
//   [12288, 18432)  W2 frags: slot s = (kc*4+nt)*64 + lane, 8 bf16 each
//   [18432, 26624)  per-wave 2048-short (4 KB) buffer (4 waves):
//       shorts 0..1535: x2 A-frags  (layer-2 input round-trip)
//       floats 0..1023 (aliased):   out-tile transpose buffer (epilogue)
// total 53248 B -> 3 blocks/CU.

template <bool BF>
__global__ __launch_bounds__(256, 3) void edge_mp_kernel(
    const float* __restrict__ h, const ushort* __restrict__ hb,
    const float* __restrict__ e_h, const float* __restrict__ ext,
    const float* __restrict__ W1, const float* __restrict__ b1,
    const float* __restrict__ W2, const float* __restrict__ b2,
    const int* __restrict__ src, const int* __restrict__ dst,
    float* __restrict__ out, int E) {
  __shared__ __align__(16) short lds[26624];
  const int tid = threadIdx.x;
  const int l = tid & 63;   // lane
  const int wid = tid >> 6; // wave in block (0..3)
  const int i = l & 15;     // MFMA idx (col of C, row of A) = edge within tile
  const int q = l >> 4;     // MFMA quad
  const int i2 = l >> 2;    // ext staging: edge within tile
  const int c = l & 3;      // ext staging: chunk lane

  // ---- stage W1 fragments (1536 slots) ----
  for (int s = tid; s < 1536; s += 256) {
    int kc = s >> 8, nt = (s >> 6) & 3, ll = s & 63;
    int k0 = kc * 32 + ((ll >> 4) * 8), n = nt * 16 + (ll & 15);
#pragma unroll
    for (int j = 0; j < 8; ++j) lds[s * 8 + j] = f2bf(W1[(k0 + j) * 64 + n]);
  }
  // ---- stage W2 fragments (768 slots) ----
  for (int s = tid; s < 768; s += 256) {
    int kc = s >> 8, nt = (s >> 6) & 3, ll = s & 63;
    int k0 = kc * 32 + ((ll >> 4) * 8), n = nt * 16 + (ll & 15);
#pragma unroll
    for (int j = 0; j < 8; ++j)
      lds[12288 + s * 8 + j] = f2bf(W2[(k0 + j) * 64 + n]);
  }
  __syncthreads();

  float b1v[4], b2v[4];
#pragma unroll
  for (int nt = 0; nt < 4; ++nt) {
    b1v[nt] = b1[nt * 16 + i];
    b2v[nt] = b2[nt * 16 + i];
  }

  short* xw = &lds[18432 + wid * 2048];
  float* ow = (float*)xw;  // aliased out-transpose buffer (1024 f32)

  // wave's edge slice: e0(it) = blockIdx.x*256 + it*64 + wid*16
  const int wbase = blockIdx.x * 256 + wid * 16;

  // prefetch first iteration's indices
  int nS = 0, nD = 0;
  if (wbase < E) {
    int e = wbase + i;
    if (e >= E) e = E - 1;
    nS = src[e];
    nD = dst[e];
  }

#pragma unroll 1
  for (int it = 0; it < ITERS; ++it) {
    const int e0 = wbase + it * 64;
    if (e0 >= E) break;
    int e = e0 + i;
    if (e >= E) e = E - 1;

    // ---- layer-1 A-fragment gathers ----
    // A-frag lane (i,q), chunk kc: elems k_local = kc_loc*32 + q*8 + j.
    bf16x8 afr[6];
    f32x4 Ls[4], Le[4], Ld[4];
    if constexpr (BF) {
      // bf16 table: one dwordx4 per source per kc chunk (16 B contiguous)
      const ushort* ps = hb + (size_t)nS * 64;
      const ushort* pd = hb + (size_t)nD * 64;
      afr[0] = *(const bf16x8*)(ps + q * 8);
      afr[1] = *(const bf16x8*)(ps + 32 + q * 8);
      afr[4] = *(const bf16x8*)(pd + q * 8);
      afr[5] = *(const bf16x8*)(pd + 32 + q * 8);
    } else {
      const float* ps = h + (size_t)nS * 64 + q * 8;
      const float* pd = h + (size_t)nD * 64 + q * 8;
      Ls[0] = *(const f32x4*)(ps);
      Ls[1] = *(const f32x4*)(ps + 4);
      Ls[2] = *(const f32x4*)(ps + 32);
      Ls[3] = *(const f32x4*)(ps + 36);
      Ld[0] = *(const f32x4*)(pd);
      Ld[1] = *(const f32x4*)(pd + 4);
      Ld[2] = *(const f32x4*)(pd + 32);
      Ld[3] = *(const f32x4*)(pd + 36);
    }
    const float* pe = e_h + (size_t)e * 64 + q * 8;
    Le[0] = *(const f32x4*)(pe);
    Le[1] = *(const f32x4*)(pe + 4);
    Le[2] = *(const f32x4*)(pe + 32);
    Le[3] = *(const f32x4*)(pe + 36);

    // ---- ext loads (coalesced, i2/c pattern) ----
    int ex = e0 + i2;
    if (ex >= E) ex = E - 1;
    f32x4 X0 = *(const f32x4*)(ext + (size_t)ex * 32 + 4 * c);
    f32x4 X1 = *(const f32x4*)(ext + (size_t)ex * 32 + 16 + 4 * c);

    // ---- prefetch next iteration's indices (off the critical chain) ----
    if (it + 1 < ITERS) {
      const int en0 = e0 + 64;
      if (en0 < E) {
        int en = en0 + i;
        if (en >= E) en = E - 1;
        nS = src[en];
        nD = dst[en];
      }
    }

    // ---- assemble remaining A-frags (e_h fp32 -> bf16; fallback h too) ----
    if constexpr (!BF) {
#pragma unroll
      for (int t = 0; t < 2; ++t) {
#pragma unroll
        for (int j = 0; j < 4; ++j) {
          afr[t][j] = f2bf(Ls[2 * t][j]);
          afr[t][4 + j] = f2bf(Ls[2 * t + 1][j]);
          afr[4 + t][j] = f2bf(Ld[2 * t][j]);
          afr[4 + t][4 + j] = f2bf(Ld[2 * t + 1][j]);
        }
      }
    }
#pragma unroll
    for (int t = 0; t < 2; ++t) {
#pragma unroll
      for (int j = 0; j < 4; ++j) {
        afr[2 + t][j] = f2bf(Le[2 * t][j]);
        afr[2 + t][4 + j] = f2bf(Le[2 * t + 1][j]);
      }
    }

    // ---- layer 1: 6 kc x 4 ntile MFMAs, A from registers ----
    f32x4 acc[4] = {{0.f, 0.f, 0.f, 0.f},
                    {0.f, 0.f, 0.f, 0.f},
                    {0.f, 0.f, 0.f, 0.f},
                    {0.f, 0.f, 0.f, 0.f}};
#pragma unroll
    for (int kc = 0; kc < 6; ++kc) {
#pragma unroll
      for (int nt = 0; nt < 4; ++nt) {
        bf16x8 b = *(const bf16x8*)&lds[((kc * 4 + nt) * 64 + l) * 8];
        acc[nt] =
            __builtin_amdgcn_mfma_f32_16x16x32_bf16(afr[kc], b, acc[nt], 0, 0, 0);
      }
    }

    // ---- x (C-layout) + b1 -> bf16 -> x2 A-layout in LDS ----
#pragma unroll
    for (int nt = 0; nt < 4; ++nt) {
      const int n = nt * 16 + i;
      const int kc2 = n >> 5, qA = (n & 31) >> 3, j = n & 7;
#pragma unroll
      for (int r = 0; r < 4; ++r) {
        const int m = q * 4 + r;  // C row = edge within tile
        xw[(kc2 * 64 + qA * 16 + m) * 8 + j] = f2bf(acc[nt][r] + b1v[nt]);
      }
    }
    // ---- ext -> x2 chunk kc2 = 2 ----
#pragma unroll
    for (int t = 0; t < 2; ++t) {
      f32x4 v = t ? X1 : X0;
      const int quad = 2 * t + (c >> 1);
      const int j0 = 4 * (c & 1);
      s16x4 p;
      p[0] = f2bf(v[0]);
      p[1] = f2bf(v[1]);
      p[2] = f2bf(v[2]);
      p[3] = f2bf(v[3]);
      *(s16x4*)&xw[(2 * 64 + quad * 16 + i2) * 8 + j0] = p;
    }

    // ---- layer 2: 3 kc x 4 ntile MFMAs ----
    f32x4 acc2[4] = {{0.f, 0.f, 0.f, 0.f},
                     {0.f, 0.f, 0.f, 0.f},
                     {0.f, 0.f, 0.f, 0.f},
                     {0.f, 0.f, 0.f, 0.f}};
#pragma unroll
    for (int kc = 0; kc < 3; ++kc) {
      bf16x8 a = *(const bf16x8*)&xw[(kc * 64 + l) * 8];
#pragma unroll
      for (int nt = 0; nt < 4; ++nt) {
        bf16x8 b = *(const bf16x8*)&lds[12288 + ((kc * 4 + nt) * 64 + l) * 8];
        acc2[nt] =
            __builtin_amdgcn_mfma_f32_16x16x32_bf16(a, b, acc2[nt], 0, 0, 0);
      }
    }

    // ---- epilogue: +b2, relu; transpose via LDS; 16 B/lane stores ----
    if (e0 + 15 < E) {
      // write C-layout f32 to LDS, bank-swizzled (2-way max = free).
#pragma unroll
      for (int nt = 0; nt < 4; ++nt) {
        const int n = nt * 16 + i;
#pragma unroll
        for (int r = 0; r < 4; ++r) {
          const int row = q * 4 + r;
          const int nsw = n ^ (((row >> 2) & 1) << 4);
          ow[row * 64 + nsw] = fmaxf(acc2[nt][r] + b2v[nt], 0.f);
        }
      }
      // read back row-major (swizzle uniform per instr) and store dwordx4.
#pragma unroll
      for (int t = 0; t < 4; ++t) {
        const int row = t * 4 + q;
        const int n0 = 4 * i;
        const int nsw = n0 ^ (((row >> 2) & 1) << 4);
        f32x4 v = *(const f32x4*)&ow[row * 64 + nsw];
        *(f32x4*)&out[(size_t)(e0 + row) * 64 + n0] = v;
      }
    } else {
      // tail tile: guarded scalar stores (C-layout)
#pragma unroll
      for (int nt = 0; nt < 4; ++nt) {
        const int n = nt * 16 + i;
#pragma unroll
        for (int r = 0; r < 4; ++r) {
          const int er = e0 + q * 4 + r;
          if (er < E) {
            float v = acc2[nt][r] + b2v[nt];
            out[(size_t)er * 64 + n] = fmaxf(v, 0.f);
          }
        }
      }
    }
  }
}

extern "C" void kernel_launch(void* const* d_in, const int* in_sizes, int n_in,
                              void* d_out, int out_size, void* d_ws,
                              size_t ws_size, hipStream_t stream) {
  const float* h = (const float*)d_in[0];
  const float* e_h = (const float*)d_in[1];
  const float* ext = (const float*)d_in[2];
  const float* W1 = (const float*)d_in[3];
  const float* b1 = (const float*)d_in[4];
  const float* W2 = (const float*)d_in[5];
  const float* b2 = (const float*)d_in[6];
  const int* src = (const int*)d_in[7];
  const int* dst = (const int*)d_in[8];
  float* out = (float*)d_out;
  const int E = in_sizes[7];   // 800000 edges
  const int nh = in_sizes[0];  // 50000*64 = 3.2M h elements
  const int blocks = (E + 255) / 256;  // 256 edges per block

  const size_t need = (size_t)nh * sizeof(ushort);
  if (d_ws && ws_size >= need && (nh & 3) == 0) {
    ushort* hb = (ushort*)d_ws;
    const int n4 = nh >> 2;
    hipLaunchKernelGGL(h2bf_kernel, dim3((n4 + 255) / 256), dim3(256), 0,
                       stream, h, hb, n4);
    hipLaunchKernelGGL(edge_mp_kernel<true>, dim3(blocks), dim3(256), 0,
                       stream, h, hb, e_h, ext, W1, b1, W2, b2, src, dst, out,
                       E);
  } else {
    hipLaunchKernelGGL(edge_mp_kernel<false>, dim3(blocks), dim3(256), 0,
                       stream, h, (const ushort*)nullptr, e_h, ext, W1, b1, W2,
                       b2, src, dst, out, E);
  }
}